// Round 9
// baseline (297.486 us; speedup 1.0000x reference)
//
#include <hip/hip_runtime.h>

// SGCN fused, MFMA v6: r6 structure (Wt in registers, swizzled g, 1 barrier/t,
// double-buffered g) + TB=4 + f16 swizzled a_t (b128 bA reads) + cross-it x prefetch.
// out[n,f,t,w] = sum_c W[c,f]*g[c,w] + b[f]*s[w],  g[c,w] = sum_v x[n,c,t,v]*a[n,t,v,w]
// x[128,256,64,32] f32, a[128,64,32,32] f32, W[256,256] f32, b[256] f32
// d_out = out (67,108,864 f32) ++ a (8,388,608 f32);  d_ws = Wt f16 [f][c] (131072 B)

#define NN 128
#define CC 256
#define TT 64
#define VV 32
#define FF 256
#define TB 4

typedef _Float16 half8 __attribute__((ext_vector_type(8)));
typedef _Float16 half4 __attribute__((ext_vector_type(4)));
typedef float floatx4 __attribute__((ext_vector_type(4)));

__global__ __launch_bounds__(256) void wt_prep_kernel(const float* __restrict__ W,
                                                      _Float16* __restrict__ Wt) {
    const int c = blockIdx.x;
    const int f = threadIdx.x;
    Wt[f * CC + c] = (_Float16)W[c * FF + f];
}

__global__ __launch_bounds__(256, 3) void sgcn_mfma6_kernel(
    const float* __restrict__ x, const float* __restrict__ a,
    const _Float16* __restrict__ Wt, const float* __restrict__ b,
    float* __restrict__ out, float* __restrict__ out_a)
{
    // a_t: rows (it*32+w) of 32 f16 v-values, 64B/row, swizzle byte ^= (row&3)<<4
    __shared__ _Float16 a_t[TB * VV * VV];      // 8 KB
    // g: 2 buffers of 32 rows (w) x 256 c f16, 512B/row, swizzle byte ^= (row&7)<<4
    __shared__ _Float16 g_s[2 * VV * 256];      // 32 KB
    __shared__ float    s_part[TB][4][VV];      // 2 KB
    __shared__ float    s_lds[TB][VV];          // 0.5 KB
    // total ~42.6 KB -> 3 blocks/CU

    const int tid  = threadIdx.x;
    const int lane = tid & 63;
    const int wv   = tid >> 6;       // wave 0..3
    const int l15  = lane & 15;
    const int lg   = lane >> 4;      // 0..3
    const int blk  = blockIdx.x;
    const int n    = blk >> 4;       // TT/TB = 16 t-groups per n
    const int t0   = (blk & 15) * TB;

    char* at_base = (char*)a_t;
    char* g_base  = (char*)g_s;

    // ---- hoist: this wave's 32 Wt fragments (f-tiles 4wv..4wv+3, all ks).
    // Issued first so their L2 latency hides under a-staging + barrier.
    half8 wb[32];
    #pragma unroll
    for (int fi = 0; fi < 4; ++fi) {
        const int f = 16 * (wv * 4 + fi) + l15;
        const _Float16* wp = Wt + (size_t)f * CC + 8 * lg;
        #pragma unroll
        for (int ks = 0; ks < 8; ++ks)
            wb[fi * 8 + ks] = *reinterpret_cast<const half8*>(wp + 32 * ks);
    }

    // ---- x prefetch for it=0 (in flight under a-staging + barrier)
    float4 xf[8];
    #pragma unroll
    for (int ci = 0; ci < 4; ++ci) {
        const int c = (wv * 4 + ci) * 16 + l15;
        const float* xp = x + (((size_t)n * CC + c) * TT + t0) * VV + 8 * lg;
        xf[ci * 2 + 0] = *reinterpret_cast<const float4*>(xp);
        xf[ci * 2 + 1] = *reinterpret_cast<const float4*>(xp + 4);
    }

    // ---- phase 0: load a (TB t's), mirror, stage transposed f16, shfl partial sums
    {
        const int v  = tid >> 3;          // 0..31  (wave wv covers v in [8wv, 8wv+8))
        const int w0 = (tid & 7) * 4;     // 0,4,...,28
        #pragma unroll
        for (int it = 0; it < TB; ++it) {
            const size_t off = ((size_t)(n * TT + t0 + it)) * (VV * VV) + tid * 4;
            float4 av = *reinterpret_cast<const float4*>(a + off);
            *reinterpret_cast<float4*>(out_a + off) = av;
            #pragma unroll
            for (int j = 0; j < 4; ++j) {
                const int row = it * VV + w0 + j;
                const float e = j == 0 ? av.x : j == 1 ? av.y : j == 2 ? av.z : av.w;
                *reinterpret_cast<_Float16*>(at_base + row * 64 +
                                             ((v * 2) ^ ((row & 3) << 4))) = (_Float16)e;
            }
            float4 p = av;                 // partial col sums over this wave's 8 v's
            #pragma unroll
            for (int m = 8; m <= 32; m <<= 1) {
                p.x += __shfl_xor(p.x, m);
                p.y += __shfl_xor(p.y, m);
                p.z += __shfl_xor(p.z, m);
                p.w += __shfl_xor(p.w, m);
            }
            if ((lane >> 3) == 0)
                *reinterpret_cast<float4*>(&s_part[it][wv][w0]) = p;
        }
    }

    float bv[4];
    #pragma unroll
    for (int fi = 0; fi < 4; ++fi) bv[fi] = b[16 * (wv * 4 + fi) + l15];

    __syncthreads();                      // a_t + s_part ready

    // ---- final s (tid<128 = (it,w)); ordered for all waves by the it=0 g-barrier
    if (tid < TB * VV) {
        const int it = tid >> 5, w = tid & 31;
        s_lds[it][w] = s_part[it][0][w] + s_part[it][1][w] +
                       s_part[it][2][w] + s_part[it][3][w];
    }

    #pragma unroll
    for (int it = 0; it < TB; ++it) {
        char* gb = g_base + (it & 1) * (VV * 256 * 2);

        // ---- bA frags for this t: one b128 each (swizzled a_t rows)
        const int r0 = it * VV + l15, r1 = r0 + 16;
        half8 bA0 = *reinterpret_cast<const half8*>(at_base + r0 * 64 +
                                                    ((16 * lg) ^ ((r0 & 3) << 4)));
        half8 bA1 = *reinterpret_cast<const half8*>(at_base + r1 * 64 +
                                                    ((16 * lg) ^ ((r1 & 3) << 4)));

        // ---- convert prefetched x -> A-frags (frees xf for the next prefetch)
        half8 af[4];
        #pragma unroll
        for (int ci = 0; ci < 4; ++ci) {
            float4 x0 = xf[ci * 2 + 0], x1 = xf[ci * 2 + 1];
            af[ci][0] = (_Float16)x0.x; af[ci][1] = (_Float16)x0.y;
            af[ci][2] = (_Float16)x0.z; af[ci][3] = (_Float16)x0.w;
            af[ci][4] = (_Float16)x1.x; af[ci][5] = (_Float16)x1.y;
            af[ci][6] = (_Float16)x1.z; af[ci][7] = (_Float16)x1.w;
        }

        // ---- prefetch x for it+1 (in flight across GEMM-A, barrier, GEMM-B)
        if (it + 1 < TB) {
            #pragma unroll
            for (int ci = 0; ci < 4; ++ci) {
                const int c = (wv * 4 + ci) * 16 + l15;
                const float* xp = x + (((size_t)n * CC + c) * TT + (t0 + it + 1)) * VV + 8 * lg;
                xf[ci * 2 + 0] = *reinterpret_cast<const float4*>(xp);
                xf[ci * 2 + 1] = *reinterpret_cast<const float4*>(xp + 4);
            }
        }

        // ---- GEMM-A: g[c,w]; write g^T rows, XOR swizzle
        #pragma unroll
        for (int ci = 0; ci < 4; ++ci) {
            const int ct = wv * 4 + ci;
            #pragma unroll
            for (int wt = 0; wt < 2; ++wt) {
                floatx4 acc = {0.f, 0.f, 0.f, 0.f};
                acc = __builtin_amdgcn_mfma_f32_16x16x32_f16(af[ci], wt ? bA1 : bA0, acc, 0, 0, 0);
                half4 gh;
                gh[0] = (_Float16)acc[0]; gh[1] = (_Float16)acc[1];
                gh[2] = (_Float16)acc[2]; gh[3] = (_Float16)acc[3];
                const int row = 16 * wt + l15;
                const int cb  = (ct * 16 + 4 * lg) * 2;
                *reinterpret_cast<half4*>(gb + row * 512 + (cb ^ ((row & 7) << 4))) = gh;
            }
        }
        __syncthreads();              // g[it&1] ready (it=0: s_lds also ordered)

        // ---- GEMM-B: D[w,f] = g^T · Wt, Wt from registers (pure LDS+MFMA)
        floatx4 acc2[8];
        #pragma unroll
        for (int q = 0; q < 8; ++q) acc2[q] = (floatx4){0.f, 0.f, 0.f, 0.f};

        __builtin_amdgcn_s_setprio(1);
        #pragma unroll
        for (int ks = 0; ks < 8; ++ks) {
            const int cb = (32 * ks + 8 * lg) * 2;
            half8 ga0 = *reinterpret_cast<const half8*>(gb + l15 * 512 +
                                                        (cb ^ ((l15 & 7) << 4)));
            half8 ga1 = *reinterpret_cast<const half8*>(gb + (16 + l15) * 512 +
                                                        (cb ^ (((16 + l15) & 7) << 4)));
            #pragma unroll
            for (int fi = 0; fi < 4; ++fi) {
                acc2[fi * 2 + 0] = __builtin_amdgcn_mfma_f32_16x16x32_f16(ga0, wb[fi * 8 + ks], acc2[fi * 2 + 0], 0, 0, 0);
                acc2[fi * 2 + 1] = __builtin_amdgcn_mfma_f32_16x16x32_f16(ga1, wb[fi * 8 + ks], acc2[fi * 2 + 1], 0, 0, 0);
            }
        }
        __builtin_amdgcn_s_setprio(0);

        // ---- epilogue: out[n,f,t,w0..3] = acc + b[f]*s[w]  (float4 stores)
        #pragma unroll
        for (int fi = 0; fi < 4; ++fi) {
            const int f = 16 * (wv * 4 + fi) + l15;
            float* ob = out + (((size_t)n * FF + f) * TT + (t0 + it)) * VV;
            #pragma unroll
            for (int mt = 0; mt < 2; ++mt) {
                const int w0 = 16 * mt + 4 * lg;
                float4 sv = *reinterpret_cast<const float4*>(&s_lds[it][w0]);
                float4 o;
                o.x = acc2[fi * 2 + mt][0] + bv[fi] * sv.x;
                o.y = acc2[fi * 2 + mt][1] + bv[fi] * sv.y;
                o.z = acc2[fi * 2 + mt][2] + bv[fi] * sv.z;
                o.w = acc2[fi * 2 + mt][3] + bv[fi] * sv.w;
                *reinterpret_cast<float4*>(ob + w0) = o;
            }
        }
        // no trailing barrier: next it writes the other g buffer; its own barrier
        // cannot be passed until every wave finished reading this one.
    }
}

// ---- fallback (verified round-3 scalar kernel): used only if ws too small
__global__ __launch_bounds__(256) void sgcn_fused_kernel(
    const float* __restrict__ x, const float* __restrict__ a,
    const float* __restrict__ W, const float* __restrict__ b,
    float* __restrict__ out, float* __restrict__ out_a)
{
    __shared__ float x_lds[CC][VV];
    __shared__ float a_lds[VV][VV];
    const int tid = threadIdx.x;
    const int nt  = blockIdx.x;
    const int n   = nt >> 6;
    const int t   = nt & 63;
    const float* xb = x + (size_t)n * CC * TT * VV + (size_t)t * VV;
    #pragma unroll
    for (int k = 0; k < 8; ++k) {
        int e = tid * 4 + k * 1024;
        int c = e >> 5, v = e & 31;
        float4 val = *reinterpret_cast<const float4*>(xb + (size_t)c * (TT * VV) + v);
        *reinterpret_cast<float4*>(&x_lds[c][v]) = val;
    }
    {
        const float* ab = a + (size_t)nt * (VV * VV);
        float4 av = *reinterpret_cast<const float4*>(ab + tid * 4);
        *reinterpret_cast<float4*>(&a_lds[0][0] + tid * 4) = av;
        *reinterpret_cast<float4*>(out_a + (size_t)nt * (VV * VV) + tid * 4) = av;
    }
    __syncthreads();
    const int f = tid;
    float h[VV];
    #pragma unroll
    for (int v = 0; v < VV; ++v) h[v] = 0.0f;
    #pragma unroll 4
    for (int c = 0; c < CC; ++c) {
        float wv = W[c * FF + f];
        #pragma unroll
        for (int v = 0; v < VV; ++v) h[v] = fmaf(x_lds[c][v], wv, h[v]);
    }
    const float bias = b[f];
    #pragma unroll
    for (int v = 0; v < VV; ++v) h[v] += bias;
    float o[VV];
    #pragma unroll
    for (int w = 0; w < VV; ++w) o[w] = 0.0f;
    #pragma unroll
    for (int v = 0; v < VV; ++v) {
        float hv = h[v];
        #pragma unroll
        for (int w = 0; w < VV; ++w) o[w] = fmaf(hv, a_lds[v][w], o[w]);
    }
    float* ob = out + (((size_t)n * FF + f) * TT + t) * VV;
    #pragma unroll
    for (int w = 0; w < VV; w += 4)
        *reinterpret_cast<float4*>(ob + w) = make_float4(o[w], o[w+1], o[w+2], o[w+3]);
}

extern "C" void kernel_launch(void* const* d_in, const int* in_sizes, int n_in,
                              void* d_out, int out_size, void* d_ws, size_t ws_size,
                              hipStream_t stream) {
    const float* x = (const float*)d_in[0];
    const float* a = (const float*)d_in[1];
    const float* W = (const float*)d_in[2];
    const float* b = (const float*)d_in[3];

    float* out   = (float*)d_out;
    float* out_a = out + (size_t)NN * FF * TT * VV;

    const size_t wt_bytes = (size_t)FF * CC * sizeof(_Float16);  // 131072

    if (ws_size >= wt_bytes) {
        _Float16* Wt = (_Float16*)d_ws;
        wt_prep_kernel<<<dim3(CC), dim3(FF), 0, stream>>>(W, Wt);
        sgcn_mfma6_kernel<<<dim3(NN * (TT / TB)), dim3(256), 0, stream>>>(x, a, Wt, b, out, out_a);
    } else {
        sgcn_fused_kernel<<<dim3(NN * TT), dim3(256), 0, stream>>>(x, a, W, b, out, out_a);
    }
}

// Round 10
// 160.128 us; speedup vs baseline: 1.8578x; 1.8578x over previous
//
#include <hip/hip_runtime.h>

// SGCN fused, MFMA v7 = r6 (162 us verified) + cross-it x prefetch, nothing else.
// out[n,f,t,w] = sum_c W[c,f]*g[c,w] + b[f]*s[w],  g[c,w] = sum_v x[n,c,t,v]*a[n,t,v,w]
// x[128,256,64,32] f32, a[128,64,32,32] f32, W[256,256] f32, b[256] f32
// d_out = out (67,108,864 f32) ++ a (8,388,608 f32);  d_ws = Wt f16 [f][c] (131072 B)

#define NN 128
#define CC 256
#define TT 64
#define VV 32
#define FF 256
#define TB 2
#define AL 33    // a_lds f32 row stride: ≡1 mod 32 -> ≤2-way on all accesses

typedef _Float16 half8 __attribute__((ext_vector_type(8)));
typedef _Float16 half4 __attribute__((ext_vector_type(4)));
typedef float floatx4 __attribute__((ext_vector_type(4)));

__global__ __launch_bounds__(256) void wt_prep_kernel(const float* __restrict__ W,
                                                      _Float16* __restrict__ Wt) {
    const int c = blockIdx.x;
    const int f = threadIdx.x;
    Wt[f * CC + c] = (_Float16)W[c * FF + f];
}

__global__ __launch_bounds__(256, 2) void sgcn_mfma7_kernel(
    const float* __restrict__ x, const float* __restrict__ a,
    const _Float16* __restrict__ Wt, const float* __restrict__ b,
    float* __restrict__ out, float* __restrict__ out_a)
{
    __shared__ float    a_lds[TB][VV][AL];      // 8448 B, f32 un-transposed
    __shared__ _Float16 g_lds[2][VV][256];      // 32 KB, row=512B, XOR-swizzled
    __shared__ float    s_lds[TB][VV];          // 256 B

    const int tid  = threadIdx.x;
    const int lane = tid & 63;
    const int wv   = tid >> 6;       // wave 0..3
    const int l15  = lane & 15;
    const int lg   = lane >> 4;      // 0..3
    const int blk  = blockIdx.x;
    const int n    = blk >> 5;       // TT/TB = 32 t-groups per n
    const int t0   = (blk & 31) * TB;

    // ---- hoist: this wave's 32 Wt fragments (f-tiles 4wv..4wv+3, all ks).
    // Issued first so their L2 latency hides under a-staging + barrier.
    half8 wb[32];
    #pragma unroll
    for (int fi = 0; fi < 4; ++fi) {
        const int f = 16 * (wv * 4 + fi) + l15;
        const _Float16* wp = Wt + (size_t)f * CC + 8 * lg;
        #pragma unroll
        for (int ks = 0; ks < 8; ++ks)
            wb[fi * 8 + ks] = *reinterpret_cast<const half8*>(wp + 32 * ks);
    }

    // ---- x prefetch for it=0 (in flight under a-staging + barrier)
    float4 xf[8];
    #pragma unroll
    for (int ci = 0; ci < 4; ++ci) {
        const int c = (wv * 4 + ci) * 16 + l15;
        const float* xp = x + (((size_t)n * CC + c) * TT + t0) * VV + 8 * lg;
        xf[ci * 2 + 0] = *reinterpret_cast<const float4*>(xp);
        xf[ci * 2 + 1] = *reinterpret_cast<const float4*>(xp + 4);
    }

    // ---- phase 0: load a (TB t's), mirror to out tail, stage f32 into LDS
    {
        const int v  = tid >> 3;
        const int w0 = (tid & 7) * 4;
        #pragma unroll
        for (int it = 0; it < TB; ++it) {
            const size_t off = ((size_t)(n * TT + t0 + it)) * (VV * VV) + tid * 4;
            float4 av = *reinterpret_cast<const float4*>(a + off);
            *reinterpret_cast<float4*>(out_a + off) = av;
            a_lds[it][v][w0 + 0] = av.x;
            a_lds[it][v][w0 + 1] = av.y;
            a_lds[it][v][w0 + 2] = av.z;
            a_lds[it][v][w0 + 3] = av.w;
        }
    }

    float bv[4];
    #pragma unroll
    for (int fi = 0; fi < 4; ++fi) bv[fi] = b[16 * (wv * 4 + fi) + l15];

    __syncthreads();                  // a_lds ready

    // ---- column sums s[it][w] (consumed after the it=0 g-barrier)
    if (tid < TB * VV) {
        const int it = tid >> 5, w = tid & 31;
        float ss = 0.0f;
        #pragma unroll
        for (int v = 0; v < VV; ++v) ss += a_lds[it][v][w];
        s_lds[it][w] = ss;
    }

    char* gbase = (char*)&g_lds[0][0][0];

    #pragma unroll
    for (int it = 0; it < TB; ++it) {
        const int buf = (it & 1) * (VV * 256 * 2);   // byte offset of g buffer

        // ---- convert prefetched x -> A-frags (frees xf for next prefetch)
        half8 af[4];
        #pragma unroll
        for (int ci = 0; ci < 4; ++ci) {
            float4 x0 = xf[ci * 2 + 0], x1 = xf[ci * 2 + 1];
            af[ci][0] = (_Float16)x0.x; af[ci][1] = (_Float16)x0.y;
            af[ci][2] = (_Float16)x0.z; af[ci][3] = (_Float16)x0.w;
            af[ci][4] = (_Float16)x1.x; af[ci][5] = (_Float16)x1.y;
            af[ci][6] = (_Float16)x1.z; af[ci][7] = (_Float16)x1.w;
        }

        // ---- cross-it prefetch: x for it+1, in flight across GEMM-A+barrier+GEMM-B
        if (it + 1 < TB) {
            #pragma unroll
            for (int ci = 0; ci < 4; ++ci) {
                const int c = (wv * 4 + ci) * 16 + l15;
                const float* xp = x + (((size_t)n * CC + c) * TT + (t0 + it + 1)) * VV + 8 * lg;
                xf[ci * 2 + 0] = *reinterpret_cast<const float4*>(xp);
                xf[ci * 2 + 1] = *reinterpret_cast<const float4*>(xp + 4);
            }
        }

        // ---- B-frags of a: col w=16wt+l15, k=v=8lg+j (scalar LDS reads, <=2-way)
        half8 bA0, bA1;
        #pragma unroll
        for (int j = 0; j < 8; ++j) {
            bA0[j] = (_Float16)a_lds[it][8 * lg + j][l15];
            bA1[j] = (_Float16)a_lds[it][8 * lg + j][16 + l15];
        }

        // ---- GEMM-A: g[c,w]; write g^T rows with XOR swizzle (byte ^= (row&7)<<4)
        #pragma unroll
        for (int ci = 0; ci < 4; ++ci) {
            const int ct = wv * 4 + ci;
            #pragma unroll
            for (int wt = 0; wt < 2; ++wt) {
                floatx4 acc = {0.f, 0.f, 0.f, 0.f};
                acc = __builtin_amdgcn_mfma_f32_16x16x32_f16(af[ci], wt ? bA1 : bA0, acc, 0, 0, 0);
                half4 gh;
                gh[0] = (_Float16)acc[0]; gh[1] = (_Float16)acc[1];
                gh[2] = (_Float16)acc[2]; gh[3] = (_Float16)acc[3];
                const int row = 16 * wt + l15;
                const int col_b = (ct * 16 + 4 * lg) * 2;            // 8B-aligned
                *reinterpret_cast<half4*>(gbase + buf + row * 512 +
                                          (col_b ^ ((row & 7) << 4))) = gh;
            }
        }
        __syncthreads();              // g[buf] ready (it=0: also s_lds ready)

        // ---- GEMM-B: D[w,f] = g^T · Wt, Wt from registers (pure LDS+MFMA)
        floatx4 acc2[8];
        #pragma unroll
        for (int q = 0; q < 8; ++q) acc2[q] = (floatx4){0.f, 0.f, 0.f, 0.f};

        __builtin_amdgcn_s_setprio(1);
        #pragma unroll
        for (int ks = 0; ks < 8; ++ks) {
            const int r0 = l15, r1 = 16 + l15;
            const int cb = (32 * ks + 8 * lg) * 2;                   // 16B-aligned
            half8 ga0 = *reinterpret_cast<const half8*>(gbase + buf + r0 * 512 +
                                                        (cb ^ ((r0 & 7) << 4)));
            half8 ga1 = *reinterpret_cast<const half8*>(gbase + buf + r1 * 512 +
                                                        (cb ^ ((r1 & 7) << 4)));
            #pragma unroll
            for (int fi = 0; fi < 4; ++fi) {
                acc2[fi * 2 + 0] = __builtin_amdgcn_mfma_f32_16x16x32_f16(ga0, wb[fi * 8 + ks], acc2[fi * 2 + 0], 0, 0, 0);
                acc2[fi * 2 + 1] = __builtin_amdgcn_mfma_f32_16x16x32_f16(ga1, wb[fi * 8 + ks], acc2[fi * 2 + 1], 0, 0, 0);
            }
        }
        __builtin_amdgcn_s_setprio(0);

        // ---- epilogue: out[n,f,t,w0..3] = acc + b[f]*s[w]  (float4 stores)
        #pragma unroll
        for (int fi = 0; fi < 4; ++fi) {
            const int f = 16 * (wv * 4 + fi) + l15;
            float* ob = out + (((size_t)n * FF + f) * TT + (t0 + it)) * VV;
            #pragma unroll
            for (int mt = 0; mt < 2; ++mt) {
                const int w0 = 16 * mt + 4 * lg;
                float4 sv = *reinterpret_cast<const float4*>(&s_lds[it][w0]);
                float4 o;
                o.x = acc2[fi * 2 + mt][0] + bv[fi] * sv.x;
                o.y = acc2[fi * 2 + mt][1] + bv[fi] * sv.y;
                o.z = acc2[fi * 2 + mt][2] + bv[fi] * sv.z;
                o.w = acc2[fi * 2 + mt][3] + bv[fi] * sv.w;
                *reinterpret_cast<float4*>(ob + w0) = o;
            }
        }
        // no trailing barrier: next it uses the other g buffer; its own barrier
        // cannot be passed until every wave finished reading this buffer.
    }
}

// ---- fallback (verified round-3 scalar kernel): used only if ws too small
__global__ __launch_bounds__(256) void sgcn_fused_kernel(
    const float* __restrict__ x, const float* __restrict__ a,
    const float* __restrict__ W, const float* __restrict__ b,
    float* __restrict__ out, float* __restrict__ out_a)
{
    __shared__ float x_lds[CC][VV];
    __shared__ float a_lds[VV][VV];
    const int tid = threadIdx.x;
    const int nt  = blockIdx.x;
    const int n   = nt >> 6;
    const int t   = nt & 63;
    const float* xb = x + (size_t)n * CC * TT * VV + (size_t)t * VV;
    #pragma unroll
    for (int k = 0; k < 8; ++k) {
        int e = tid * 4 + k * 1024;
        int c = e >> 5, v = e & 31;
        float4 val = *reinterpret_cast<const float4*>(xb + (size_t)c * (TT * VV) + v);
        *reinterpret_cast<float4*>(&x_lds[c][v]) = val;
    }
    {
        const float* ab = a + (size_t)nt * (VV * VV);
        float4 av = *reinterpret_cast<const float4*>(ab + tid * 4);
        *reinterpret_cast<float4*>(&a_lds[0][0] + tid * 4) = av;
        *reinterpret_cast<float4*>(out_a + (size_t)nt * (VV * VV) + tid * 4) = av;
    }
    __syncthreads();
    const int f = tid;
    float h[VV];
    #pragma unroll
    for (int v = 0; v < VV; ++v) h[v] = 0.0f;
    #pragma unroll 4
    for (int c = 0; c < CC; ++c) {
        float wv = W[c * FF + f];
        #pragma unroll
        for (int v = 0; v < VV; ++v) h[v] = fmaf(x_lds[c][v], wv, h[v]);
    }
    const float bias = b[f];
    #pragma unroll
    for (int v = 0; v < VV; ++v) h[v] += bias;
    float o[VV];
    #pragma unroll
    for (int w = 0; w < VV; ++w) o[w] = 0.0f;
    #pragma unroll
    for (int v = 0; v < VV; ++v) {
        float hv = h[v];
        #pragma unroll
        for (int w = 0; w < VV; ++w) o[w] = fmaf(hv, a_lds[v][w], o[w]);
    }
    float* ob = out + (((size_t)n * FF + f) * TT + t) * VV;
    #pragma unroll
    for (int w = 0; w < VV; w += 4)
        *reinterpret_cast<float4*>(ob + w) = make_float4(o[w], o[w+1], o[w+2], o[w+3]);
}

extern "C" void kernel_launch(void* const* d_in, const int* in_sizes, int n_in,
                              void* d_out, int out_size, void* d_ws, size_t ws_size,
                              hipStream_t stream) {
    const float* x = (const float*)d_in[0];
    const float* a = (const float*)d_in[1];
    const float* W = (const float*)d_in[2];
    const float* b = (const float*)d_in[3];

    float* out   = (float*)d_out;
    float* out_a = out + (size_t)NN * FF * TT * VV;

    const size_t wt_bytes = (size_t)FF * CC * sizeof(_Float16);  // 131072

    if (ws_size >= wt_bytes) {
        _Float16* Wt = (_Float16*)d_ws;
        wt_prep_kernel<<<dim3(CC), dim3(FF), 0, stream>>>(W, Wt);
        sgcn_mfma7_kernel<<<dim3(NN * (TT / TB)), dim3(256), 0, stream>>>(x, a, Wt, b, out, out_a);
    } else {
        sgcn_fused_kernel<<<dim3(NN * TT), dim3(256), 0, stream>>>(x, a, W, b, out, out_a);
    }
}